// Round 1
// baseline (1529.692 us; speedup 1.0000x reference)
//
#include <hip/hip_runtime.h>
#include <math.h>

#define NN 500000
#define BLOCK 256
#define NUM_GRAPHS 4096

// lane = node. Weights are wave-uniform -> scalar loads (SMEM pipe).
// Activations staged coalesced global->LDS, odd stride padding (33 / 25).
// Phase A: MLP (64 acc). Phase B: spherical (96 acc). Segmented-scan scatter.
__global__ __launch_bounds__(256) void vecout_kernel(
    const float* __restrict__ x_scalar,
    const float* __restrict__ x_sph,
    const int* __restrict__ bidx,
    const float* __restrict__ W1,
    const float* __restrict__ b1,
    const float* __restrict__ W2,
    const float* __restrict__ b2,
    const float* __restrict__ Wsph1,
    const float* __restrict__ Wsph2,
    float* __restrict__ out)
{
    __shared__ float tile[256 * 33];   // 33.8 KB; reused by both phases
    const int t = threadIdx.x;
    const int node = blockIdx.x * BLOCK + t;
    const bool valid = node < NN;

    // ---------------- Phase A: scalar MLP head ----------------
    float acc[64];
    #pragma unroll
    for (int j = 0; j < 64; ++j) acc[j] = b1[j];

    for (int kc = 0; kc < 128; kc += 32) {
        __syncthreads();
        // stage x_scalar[:, kc:kc+32] for this block's 256 nodes (coalesced)
        #pragma unroll 4
        for (int it = 0; it < 32; ++it) {
            int flat = it * 256 + t;
            int row = flat >> 5;
            int col = flat & 31;
            int grow = blockIdx.x * BLOCK + row;
            if (grow >= NN) grow = NN - 1;
            tile[row * 33 + col] = x_scalar[grow * 128 + kc + col];
        }
        __syncthreads();
        const float* xrow = &tile[t * 33];
        // split hid into halves so only 32 uniform weights are live at a time
        for (int jh = 0; jh < 2; ++jh) {
            float* acch = acc + jh * 32;
            #pragma unroll 2
            for (int k = 0; k < 32; ++k) {
                float xk = xrow[k];
                const float* wr = W1 + (kc + k) * 64 + jh * 32;
                #pragma unroll
                for (int j = 0; j < 32; ++j)
                    acch[j] = fmaf(xk, wr[j], acch[j]);
            }
        }
    }
    // s = silu(acc) @ W2 + b2
    float s = b2[0];
    #pragma unroll
    for (int j = 0; j < 64; ++j) {
        float a = acc[j];
        float sig = 1.0f / (1.0f + __expf(-a));
        s = fmaf(a * sig, W2[j], s);
    }

    // ---------------- Phase B: spherical (l=1) channel ----------------
    // h[o][i] = sum_c x1e[c][i] * Wsph1[c][o]; x1e[c][i] = x_sph[128 + 3c + i]
    float h0[32], h1[32], h2[32];
    #pragma unroll
    for (int o = 0; o < 32; ++o) { h0[o] = 0.f; h1[o] = 0.f; h2[o] = 0.f; }

    for (int cc = 0; cc < 8; ++cc) {             // 8 chunks of 8 c's (24 cols)
        __syncthreads();
        // stage x_sph[:, 128+24*cc : 128+24*cc+24] (coalesced, stride-25 LDS)
        {
            int row = t / 24;
            int col = t - row * 24;
            const int gbase = 128 + cc * 24;
            #pragma unroll 4
            for (int it = 0; it < 24; ++it) {
                int grow = blockIdx.x * BLOCK + row;
                if (grow >= NN) grow = NN - 1;
                tile[row * 25 + col] = x_sph[grow * 480 + gbase + col];
                row += 10; col += 16;            // advance flat index by 256
                if (col >= 24) { col -= 24; row += 1; }
            }
        }
        __syncthreads();
        const float* xr = &tile[t * 25];
        #pragma unroll 2
        for (int c = 0; c < 8; ++c) {
            float x0 = xr[3 * c + 0];
            float x1 = xr[3 * c + 1];
            float x2 = xr[3 * c + 2];
            const float* wr = Wsph1 + (cc * 8 + c) * 32;
            #pragma unroll
            for (int o = 0; o < 32; ++o) {
                float w = wr[o];
                h0[o] = fmaf(x0, w, h0[o]);
                h1[o] = fmaf(x1, w, h1[o]);
                h2[o] = fmaf(x2, w, h2[o]);
            }
        }
    }

    // gate = sigmoid(|h/8|); vec_i = sum_o (h/8)*gate*Wsph2[o] / sqrt(32)
    float v0 = 0.f, v1 = 0.f, v2 = 0.f;
    #pragma unroll
    for (int o = 0; o < 32; ++o) {
        float n2 = h0[o] * h0[o] + h1[o] * h1[o] + h2[o] * h2[o];
        float nrm = 0.125f * sqrtf(n2);
        float gate = 1.0f / (1.0f + __expf(-nrm));
        float gw = gate * Wsph2[o];
        v0 = fmaf(h0[o], gw, v0);
        v1 = fmaf(h1[o], gw, v1);
        v2 = fmaf(h2[o], gw, v2);
    }
    const float VS = 0.125f / 5.656854249492381f;   // (1/8)/sqrt(32)
    v0 *= VS; v1 *= VS; v2 *= VS;

    // permute [2,0,1], multiply by scalar
    float a0 = v2 * s, a1 = v0 * s, a2 = v1 * s;

    int g = valid ? bidx[node] : -1;
    if (!valid) { a0 = 0.f; a1 = 0.f; a2 = 0.f; }

    // segmented inclusive scan over the wave (nodes contiguous, bidx sorted)
    const int lane = t & 63;
    #pragma unroll
    for (int d = 1; d < 64; d <<= 1) {
        int   og = __shfl_up(g, d, 64);
        float o0 = __shfl_up(a0, d, 64);
        float o1 = __shfl_up(a1, d, 64);
        float o2 = __shfl_up(a2, d, 64);
        if (lane >= d && og == g) { a0 += o0; a1 += o1; a2 += o2; }
    }
    int gn = __shfl_down(g, 1, 64);
    bool lastlane = (lane == 63) || (gn != g);
    if (valid && lastlane) {
        atomicAdd(&out[g * 3 + 0], a0);
        atomicAdd(&out[g * 3 + 1], a1);
        atomicAdd(&out[g * 3 + 2], a2);
    }
}

extern "C" void kernel_launch(void* const* d_in, const int* in_sizes, int n_in,
                              void* d_out, int out_size, void* d_ws, size_t ws_size,
                              hipStream_t stream) {
    const float* x_scalar = (const float*)d_in[0];
    const float* x_sph    = (const float*)d_in[1];
    // d_in[2] = coord (unused by reference)
    const int*   bidx     = (const int*)d_in[3];
    // d_in[4] = num_segments scalar (4096)
    const float* W1    = (const float*)d_in[5];
    const float* b1    = (const float*)d_in[6];
    const float* W2    = (const float*)d_in[7];
    const float* b2    = (const float*)d_in[8];
    const float* Wsph1 = (const float*)d_in[9];
    const float* Wsph2 = (const float*)d_in[10];
    float* out = (float*)d_out;

    hipMemsetAsync(out, 0, (size_t)out_size * sizeof(float), stream);

    int grid = (NN + BLOCK - 1) / BLOCK;   // 1954
    vecout_kernel<<<grid, BLOCK, 0, stream>>>(
        x_scalar, x_sph, bidx, W1, b1, W2, b2, Wsph1, Wsph2, out);
}